// Round 4
// baseline (607.045 us; speedup 1.0000x reference)
//
#include <hip/hip_runtime.h>

#define N_NODES 50000
#define N_EDGES 640000
#define HID 128
#define EF 16
#define NLAYERS 3
#define CHUNK 16
#define SCAN_BLOCKS 196  // ceil(50000/256)
#define EMS 132          // em_s row stride in floats (pad 4 -> 2-way banks only)

typedef __attribute__((ext_vector_type(8))) short short8;
typedef __attribute__((ext_vector_type(4))) float f32x4;
typedef __attribute__((ext_vector_type(2))) float f32x2;

__device__ __forceinline__ unsigned short f2bf(float f) {
  unsigned int u = __float_as_uint(f);
  u = u + 0x7FFFu + ((u >> 16) & 1u);  // RNE
  return (unsigned short)(u >> 16);
}

// 8-lane butterfly sum via DPP: xor1 (quad_perm), xor2 (quad_perm), mirror-within-8.
__device__ __forceinline__ float dpp_hadd8(float v) {
  int x;
  x = __builtin_amdgcn_update_dpp(0, __float_as_int(v), 0xB1, 0xF, 0xF, true);
  v += __int_as_float(x);
  x = __builtin_amdgcn_update_dpp(0, __float_as_int(v), 0x4E, 0xF, 0xF, true);
  v += __int_as_float(x);
  x = __builtin_amdgcn_update_dpp(0, __float_as_int(v), 0x141, 0xF, 0xF, true);
  v += __int_as_float(x);
  return v;
}

// channel j = h*16+c -> paired slot: lane l = h*8 + (c&7) holds halves c>>3.
// slot(j) = l*2 + (c>>3). Both of a lane's channels share head h = l>>3.
__device__ __forceinline__ int pslot(int j) {
  return (((j >> 4) * 8 + (j & 7)) << 1) + ((j >> 3) & 1);
}

// Mt[l][k][slot(j)] = sum_i Wt[k,i] * We[l][i,j]   (16x128 per layer, paired cols)
// ct[l][slot(j)]    = sum_i bt[i]  * We[l][i,j]
__global__ __launch_bounds__(256) void k_prep(const float* __restrict__ Wt,
                                              const float* __restrict__ bt,
                                              const float* __restrict__ We,
                                              float* __restrict__ Mt,
                                              float* __restrict__ ct) {
  int id = blockIdx.x * 256 + threadIdx.x;
  const int total = NLAYERS * (EF + 1) * HID;
  if (id >= total) return;
  int l = id / ((EF + 1) * HID);
  int r = id % ((EF + 1) * HID);
  int row = r / HID;
  int j = r % HID;
  const float* Wel = We + l * HID * HID;
  float s = 0.f;
  if (row < EF) {
    const float* wtr = Wt + row * HID;
    for (int i = 0; i < HID; ++i) s += wtr[i] * Wel[i * HID + j];
    Mt[(l * EF + row) * HID + pslot(j)] = s;
  } else {
    for (int i = 0; i < HID; ++i) s += bt[i] * Wel[i * HID + j];
    ct[l * HID + pslot(j)] = s;
  }
}

// B-fragment table for the em MFMA: MtB[l][t][lane][j] (j=0..7, bf16).
// Tile t covers slots [16t,16t+16); lane: n = 16t+(lane&15), k = (lane>>4)*8+j
// (k>=16, i.e. lane groups 2..3, are zero -> K padded 16->32).
__global__ __launch_bounds__(256) void k_prepb(const float* __restrict__ Mt,
                                               unsigned short* __restrict__ MtB) {
  int id = blockIdx.x * 256 + threadIdx.x;
  const int total = NLAYERS * 8 * 64 * 8;
  if (id >= total) return;
  int j = id & 7;
  int lane = (id >> 3) & 63;
  int t = (id >> 9) & 7;
  int l = id >> 12;
  int g = lane >> 4;
  unsigned short v = 0;
  if (g < 2) {
    int k = g * 8 + j;
    v = f2bf(Mt[(l * EF + k) * HID + t * 16 + (lane & 15)]);
  }
  MtB[id] = v;
}

// x0 (fp32) -> bf16
__global__ __launch_bounds__(256) void k_cvtx(const float* __restrict__ x,
                                              unsigned short* __restrict__ xbf) {
  int id = blockIdx.x * 256 + threadIdx.x;  // one per 8 elements
  const int total = N_NODES * HID / 8;
  if (id >= total) return;
  const float4* p = (const float4*)(x + id * 8);
  float4 a = p[0], b = p[1];
  unsigned short o[8] = {f2bf(a.x), f2bf(a.y), f2bf(a.z), f2bf(a.w),
                         f2bf(b.x), f2bf(b.y), f2bf(b.z), f2bf(b.w)};
  *(uint4*)(xbf + id * 8) = *(uint4*)o;
}

// WT_bf[l][s][n][k] = bf16( W_s[l][k][n] ),  s=0 -> Wl, s=1 -> Wr
__global__ __launch_bounds__(256) void k_cvtw(const float* __restrict__ Wl,
                                              const float* __restrict__ Wr,
                                              unsigned short* __restrict__ WT) {
  int id = blockIdx.x * 256 + threadIdx.x;
  const int total = NLAYERS * 2 * HID * HID;
  if (id >= total) return;
  int k = id & (HID - 1);
  int n = (id >> 7) & (HID - 1);
  int s = (id >> 14) & 1;
  int l = id >> 15;
  const float* W = (s == 0 ? Wl : Wr) + (size_t)l * HID * HID;
  WT[id] = f2bf(W[k * HID + n]);
}

__global__ __launch_bounds__(256) void k_zero(int* __restrict__ counts, int* __restrict__ fill) {
  int id = blockIdx.x * 256 + threadIdx.x;
  if (id < N_NODES) { counts[id] = 0; fill[id] = 0; }
}

__global__ __launch_bounds__(256) void k_hist(const int* __restrict__ dst, int* __restrict__ counts) {
  int e = blockIdx.x * 256 + threadIdx.x;
  if (e < N_EDGES) atomicAdd(&counts[dst[e]], 1);
}

__global__ __launch_bounds__(256) void k_scan1(const int* __restrict__ counts,
                                               int* __restrict__ rowptr,
                                               int* __restrict__ bsum) {
  __shared__ int sc[256];
  int t = threadIdx.x;
  int i = blockIdx.x * 256 + t;
  int v = (i < N_NODES) ? counts[i] : 0;
  sc[t] = v;
  __syncthreads();
  for (int off = 1; off < 256; off <<= 1) {
    int u = 0;
    if (t >= off) u = sc[t - off];
    __syncthreads();
    sc[t] += u;
    __syncthreads();
  }
  if (i < N_NODES) rowptr[i] = sc[t] - v;  // block-local exclusive
  if (t == 255) bsum[blockIdx.x] = sc[255];
}

__global__ __launch_bounds__(256) void k_scan2(int* __restrict__ bsum) {
  __shared__ int sc[256];
  int t = threadIdx.x;
  int v = (t < SCAN_BLOCKS) ? bsum[t] : 0;
  sc[t] = v;
  __syncthreads();
  for (int off = 1; off < 256; off <<= 1) {
    int u = 0;
    if (t >= off) u = sc[t - off];
    __syncthreads();
    sc[t] += u;
    __syncthreads();
  }
  bsum[t] = sc[t] - v;  // exclusive block offsets
}

__global__ __launch_bounds__(256) void k_scan3(int* __restrict__ rowptr, const int* __restrict__ bsum) {
  int t = threadIdx.x;
  int i = blockIdx.x * 256 + t;
  if (i < N_NODES) rowptr[i] += bsum[blockIdx.x];
  if (i == 0) rowptr[N_NODES] = N_EDGES;
}

__global__ __launch_bounds__(256) void k_fill(const int* __restrict__ src,
                                              const int* __restrict__ dst,
                                              const int* __restrict__ rowptr,
                                              int* __restrict__ fill,
                                              int* __restrict__ ssrc,
                                              int* __restrict__ seid) {
  int e = blockIdx.x * 256 + threadIdx.x;
  if (e >= N_EDGES) return;
  int d = dst[e];
  int pos = atomicAdd(&fill[d], 1);
  int idx = rowptr[d] + pos;
  ssrc[idx] = src[e];
  seid[idx] = e;
}

// bf16 MFMA node GEMM: out_s = x @ W_s + b_s, written in channel-PAIRED layout.
// Block: 64 rows x 128 cols, blockIdx.y selects s (0 -> xl, 1 -> xr).
__global__ __launch_bounds__(256) void k_gemm_mfma(const unsigned short* __restrict__ xbf,
                                                   const unsigned short* __restrict__ WTl,  // layer base: [2][128][128]
                                                   const float* __restrict__ bl,
                                                   const float* __restrict__ br,
                                                   float* __restrict__ xl,
                                                   float* __restrict__ xr) {
  __shared__ short As[64 * 136];
  __shared__ short Bs[128 * 136];
  int t = threadIdx.x;
  int s = blockIdx.y;
  int row0 = blockIdx.x * 64;

  // stage A: 64 rows x 128 bf16, 16B chunks
  const uint4* gx = (const uint4*)xbf;
#pragma unroll
  for (int p = 0; p < 4; ++p) {
    int c = t + p * 256;
    int row = c >> 4, col16 = c & 15;
    int grow = row0 + row;
    if (grow >= N_NODES) grow = N_NODES - 1;
    uint4 v = gx[grow * 16 + col16];
    *(uint4*)(&As[row * 136 + col16 * 8]) = v;
  }
  // stage B: 128 rows (n) x 128 bf16 of WT[s]
  const uint4* gw = (const uint4*)WTl;
#pragma unroll
  for (int p = 0; p < 8; ++p) {
    int c = t + p * 256;
    int row = c >> 4, col16 = c & 15;
    uint4 v = gw[s * 2048 + row * 16 + col16];
    *(uint4*)(&Bs[row * 136 + col16 * 8]) = v;
  }
  __syncthreads();

  int lane = t & 63, w = t >> 6;
  int quad = lane >> 4, lm = lane & 15;
  f32x4 acc[4][2];
#pragma unroll
  for (int mf = 0; mf < 4; ++mf)
#pragma unroll
    for (int nf = 0; nf < 2; ++nf) acc[mf][nf] = (f32x4)(0.f);

#pragma unroll
  for (int ks = 0; ks < 4; ++ks) {
    short8 af[4], bf[2];
#pragma unroll
    for (int mf = 0; mf < 4; ++mf)
      af[mf] = *(short8*)(&As[(mf * 16 + lm) * 136 + ks * 32 + quad * 8]);
#pragma unroll
    for (int nf = 0; nf < 2; ++nf)
      bf[nf] = *(short8*)(&Bs[(w * 32 + nf * 16 + lm) * 136 + ks * 32 + quad * 8]);
#pragma unroll
    for (int mf = 0; mf < 4; ++mf)
#pragma unroll
      for (int nf = 0; nf < 2; ++nf)
        acc[mf][nf] = __builtin_amdgcn_mfma_f32_16x16x32_bf16(af[mf], bf[nf], acc[mf][nf], 0, 0, 0);
  }

  const float* bias = (s == 0) ? bl : br;
  float* out = (s == 0) ? xl : xr;
#pragma unroll
  for (int nf = 0; nf < 2; ++nf) {
    int n = w * 32 + nf * 16 + lm;
    float bv = bias[n];
    int slot = pslot(n);
#pragma unroll
    for (int mf = 0; mf < 4; ++mf) {
#pragma unroll
      for (int r = 0; r < 4; ++r) {
        int grow = row0 + mf * 16 + quad * 4 + r;
        if (grow < N_NODES) out[grow * HID + slot] = acc[mf][nf][r] + bv;
      }
    }
  }
}

// ONE WAVE per destination node; lane l owns channels j0=(l>>3)*16+(l&7) and
// j0+8 — SAME head => one logit reduce (3 DPP) + one exp per edge.
// em computed per 16-edge chunk by 8x mfma_f32_16x16x32_bf16 (K zero-padded),
// round-tripped through LDS; edge loop reads it as one ds_read_b64.
__global__ __launch_bounds__(64) void k_fused(const float* __restrict__ xin,
                                              const float* __restrict__ xl,   // paired
                                              const float* __restrict__ xr,   // paired
                                              const float* __restrict__ eattr,
                                              const int* __restrict__ rowptr,
                                              const int* __restrict__ ssrc,
                                              const int* __restrict__ seid,
                                              const unsigned short* __restrict__ MtB,  // layer base
                                              const float* __restrict__ ct,   // paired
                                              const float* __restrict__ att,
                                              const float* __restrict__ bias_o,
                                              const float* __restrict__ lng,
                                              const float* __restrict__ lnb,
                                              float* __restrict__ xout,
                                              unsigned short* __restrict__ xbf_out) {
  __shared__ float em_s[CHUNK * EMS];
  __shared__ int src_s[CHUNK];
  int n = blockIdx.x;
  int l = threadIdx.x;  // lane 0..63
  int g = l >> 4, e16 = l & 15;
  int j0 = (l >> 3) * 16 + (l & 7), j1 = j0 + 8;

  short8 btile[8];
#pragma unroll
  for (int t = 0; t < 8; ++t)
    btile[t] = *(const short8*)(MtB + (t * 64 + l) * 8);

  f32x2 base = *(const f32x2*)(&xr[(size_t)n * HID + l * 2]) +
               *(const f32x2*)(&ct[l * 2]);
  f32x2 attp = {att[j0], att[j1]};
  int beg = rowptr[n], end = rowptr[n + 1];
  f32x2 acc = {0.f, 0.f};
  float denom = 0.f;

  for (int c0 = beg; c0 < end; c0 += CHUNK) {
    int cnt = min(CHUNK, end - c0);
    __syncthreads();
    // stage A-fragment: lane l -> edge (l&15), feats (l>>4)*8..+7 (groups 2,3 zero)
    int eix = c0 + e16;
    if (eix > N_EDGES - 1) eix = N_EDGES - 1;
    int e = seid[eix];
    short8 af = {0, 0, 0, 0, 0, 0, 0, 0};
    if (g < 2) {
      const float4* pe = (const float4*)(eattr + (size_t)e * EF + g * 8);
      float4 u0 = pe[0], u1 = pe[1];
      af[0] = (short)f2bf(u0.x); af[1] = (short)f2bf(u0.y);
      af[2] = (short)f2bf(u0.z); af[3] = (short)f2bf(u0.w);
      af[4] = (short)f2bf(u1.x); af[5] = (short)f2bf(u1.y);
      af[6] = (short)f2bf(u1.z); af[7] = (short)f2bf(u1.w);
    }
    if (l < CHUNK) src_s[l] = ssrc[eix];
    // em chunk: EA(16x32,zero-pad) @ Mt(32x128) -> 8 tiles of 16x16
    f32x4 emacc[8];
#pragma unroll
    for (int t = 0; t < 8; ++t)
      emacc[t] = __builtin_amdgcn_mfma_f32_16x16x32_bf16(af, btile[t], (f32x4)(0.f), 0, 0, 0);
    // C layout: row(edge) = g*4 + r, col(slot) = 16t + (l&15)
#pragma unroll
    for (int t = 0; t < 8; ++t)
#pragma unroll
      for (int r = 0; r < 4; ++r)
        em_s[(g * 4 + r) * EMS + t * 16 + e16] = emacc[t][r];
    __syncthreads();

    for (int i = 0; i < cnt; ++i) {
      int s = src_s[i];
      f32x2 xls = *(const f32x2*)(xl + (size_t)s * HID + l * 2);
      f32x2 em = *(const f32x2*)(&em_s[i * EMS + l * 2]);
      f32x2 m = base + xls + em;
      // leaky_relu(m, 0.2) = 0.6*m + 0.4*|m|
      f32x2 am = {__int_as_float(__float_as_int(m.x) & 0x7FFFFFFF),
                  __int_as_float(__float_as_int(m.y) & 0x7FFFFFFF)};
      m = 0.6f * m + 0.4f * am;
      f32x2 v2 = m * attp;
      float vs = dpp_hadd8(v2.x + v2.y);  // head logit (8 lanes share head)
      float p = __expf(vs);               // logits small: no max-subtract
      denom += p;
      acc += xls * p;
    }
  }

  f32x2 outp;
  float inv = 1.f / (denom + 1e-16f);
  outp.x = acc.x * inv + bias_o[j0];
  outp.y = acc.y * inv + bias_o[j1];
  // LayerNorm over 128 channels: pair-sum then 64-lane butterfly (single wave)
  float s1 = outp.x + outp.y;
  float s2 = outp.x * outp.x + outp.y * outp.y;
#pragma unroll
  for (int mask = 1; mask <= 32; mask <<= 1) {
    s1 += __shfl_xor(s1, mask);
    s2 += __shfl_xor(s2, mask);
  }
  float mu = s1 * (1.f / 128.f);
  float var = s2 * (1.f / 128.f) - mu * mu;
  float rs = rsqrtf(var + 1e-5f);
  float y0 = lng[j0] * (outp.x - mu) * rs + lnb[j0];
  float y1 = lng[j1] * (outp.y - mu) * rs + lnb[j1];
  float r0 = fmaxf(y0, 0.f) + xin[(size_t)n * HID + j0];
  float r1 = fmaxf(y1, 0.f) + xin[(size_t)n * HID + j1];
  xout[(size_t)n * HID + j0] = r0;
  xout[(size_t)n * HID + j1] = r1;
  xbf_out[(size_t)n * HID + j0] = f2bf(r0);
  xbf_out[(size_t)n * HID + j1] = f2bf(r1);
}

extern "C" void kernel_launch(void* const* d_in, const int* in_sizes, int n_in,
                              void* d_out, int out_size, void* d_ws, size_t ws_size,
                              hipStream_t stream) {
  const float* x0    = (const float*)d_in[0];
  const int*   eidx  = (const int*)d_in[2];
  const float* eattr = (const float*)d_in[3];
  const float* Wt    = (const float*)d_in[4];
  const float* bt    = (const float*)d_in[5];
  const float* Wl    = (const float*)d_in[6];
  const float* bl    = (const float*)d_in[7];
  const float* Wr    = (const float*)d_in[8];
  const float* br    = (const float*)d_in[9];
  const float* We    = (const float*)d_in[10];
  const float* att   = (const float*)d_in[11];
  const float* bo    = (const float*)d_in[12];
  const float* lng   = (const float*)d_in[13];
  const float* lnb   = (const float*)d_in[14];
  float* out = (float*)d_out;
  const int* src = eidx;
  const int* dst = eidx + N_EDGES;

  char* ws = (char*)d_ws;
  size_t off = 0;
  auto alloc = [&](size_t bytes) {
    char* p = ws + off;
    off += (bytes + 255) & ~(size_t)255;
    return p;
  };
  float* Mt   = (float*)alloc((size_t)NLAYERS * EF * HID * 4);
  float* ct   = (float*)alloc((size_t)NLAYERS * HID * 4);
  int* counts = (int*)alloc((size_t)N_NODES * 4);
  int* rowptr = (int*)alloc((size_t)(N_NODES + 1) * 4);
  int* bsum   = (int*)alloc(256 * 4);
  int* fill   = (int*)alloc((size_t)N_NODES * 4);
  int* ssrc   = (int*)alloc((size_t)N_EDGES * 4);
  int* seid   = (int*)alloc((size_t)N_EDGES * 4);
  float* xl   = (float*)alloc((size_t)N_NODES * HID * 4);
  float* xr   = (float*)alloc((size_t)N_NODES * HID * 4);
  float* xbuf = (float*)alloc((size_t)N_NODES * HID * 4);
  unsigned short* xbf = (unsigned short*)alloc((size_t)N_NODES * HID * 2);
  unsigned short* WTb = (unsigned short*)alloc((size_t)NLAYERS * 2 * HID * HID * 2);
  unsigned short* MtBb = (unsigned short*)alloc((size_t)NLAYERS * 8 * 64 * 8 * 2);

  hipLaunchKernelGGL(k_prep, dim3(26), dim3(256), 0, stream, Wt, bt, We, Mt, ct);
  hipLaunchKernelGGL(k_prepb, dim3((NLAYERS * 8 * 64 * 8 + 255) / 256), dim3(256), 0, stream, Mt, MtBb);
  hipLaunchKernelGGL(k_cvtx, dim3((N_NODES * HID / 8 + 255) / 256), dim3(256), 0, stream, x0, xbf);
  hipLaunchKernelGGL(k_cvtw, dim3((NLAYERS * 2 * HID * HID + 255) / 256), dim3(256), 0, stream, Wl, Wr, WTb);
  hipLaunchKernelGGL(k_zero, dim3(SCAN_BLOCKS), dim3(256), 0, stream, counts, fill);
  hipLaunchKernelGGL(k_hist, dim3((N_EDGES + 255) / 256), dim3(256), 0, stream, dst, counts);
  hipLaunchKernelGGL(k_scan1, dim3(SCAN_BLOCKS), dim3(256), 0, stream, counts, rowptr, bsum);
  hipLaunchKernelGGL(k_scan2, dim3(1), dim3(256), 0, stream, bsum);
  hipLaunchKernelGGL(k_scan3, dim3(SCAN_BLOCKS), dim3(256), 0, stream, rowptr, bsum);
  hipLaunchKernelGGL(k_fill, dim3((N_EDGES + 255) / 256), dim3(256), 0, stream,
                     src, dst, rowptr, fill, ssrc, seid);

  for (int l = 0; l < NLAYERS; ++l) {
    const float* xin = (l == 0) ? x0 : (const float*)xbuf;
    float* xout = (l == NLAYERS - 1) ? out : xbuf;
    hipLaunchKernelGGL(k_gemm_mfma, dim3((N_NODES + 63) / 64, 2), dim3(256), 0, stream,
                       xbf, WTb + (size_t)l * 2 * HID * HID, bl + l * HID, br + l * HID, xl, xr);
    hipLaunchKernelGGL(k_fused, dim3(N_NODES), dim3(64), 0, stream,
                       xin, xl, xr, eattr, rowptr, ssrc, seid,
                       MtBb + (size_t)l * 8 * 64 * 8, ct + l * HID, att + l * HID,
                       bo + l * HID, lng + l * HID, lnb + l * HID, xout, xbf);
  }
}

// Round 5
// 509.202 us; speedup vs baseline: 1.1921x; 1.1921x over previous
//
#include <hip/hip_runtime.h>

#define N_NODES 50000
#define N_EDGES 640000
#define HID 128
#define EF 16
#define NLAYERS 3
#define CHUNK 32
#define SCAN_BLOCKS 196  // ceil(50000/256)

typedef __attribute__((ext_vector_type(8))) short short8;
typedef __attribute__((ext_vector_type(4))) float f32x4;
typedef __attribute__((ext_vector_type(2))) float f32x2;

__device__ __forceinline__ unsigned short f2bf(float f) {
  unsigned int u = __float_as_uint(f);
  u = u + 0x7FFFu + ((u >> 16) & 1u);  // RNE
  return (unsigned short)(u >> 16);
}

// 8-lane butterfly sum via DPP: xor1, xor2 (quad_perm), then half-row mirror.
// Reduces within each aligned group of 8 lanes (one head).
__device__ __forceinline__ float dpp_hadd8(float v) {
  int x;
  x = __builtin_amdgcn_update_dpp(0, __float_as_int(v), 0xB1, 0xF, 0xF, true);
  v += __int_as_float(x);
  x = __builtin_amdgcn_update_dpp(0, __float_as_int(v), 0x4E, 0xF, 0xF, true);
  v += __int_as_float(x);
  x = __builtin_amdgcn_update_dpp(0, __float_as_int(v), 0x141, 0xF, 0xF, true);
  v += __int_as_float(x);
  return v;
}

// channel j = h*16+c -> paired slot: lane l = h*8 + (c&7) holds halves c>>3.
// slot(j) = l*2 + (c>>3). Both of a lane's channels share head h = l>>3.
__device__ __forceinline__ int pslot(int j) {
  return (((j >> 4) * 8 + (j & 7)) << 1) + ((j >> 3) & 1);
}

// Mt[l][k][slot(j)] = sum_i Wt[k,i] * We[l][i,j]   (16x128 per layer, paired cols)
// ct[l][slot(j)]    = sum_i bt[i]  * We[l][i,j]
__global__ __launch_bounds__(256) void k_prep(const float* __restrict__ Wt,
                                              const float* __restrict__ bt,
                                              const float* __restrict__ We,
                                              float* __restrict__ Mt,
                                              float* __restrict__ ct) {
  int id = blockIdx.x * 256 + threadIdx.x;
  const int total = NLAYERS * (EF + 1) * HID;
  if (id >= total) return;
  int l = id / ((EF + 1) * HID);
  int r = id % ((EF + 1) * HID);
  int row = r / HID;
  int j = r % HID;
  const float* Wel = We + l * HID * HID;
  float s = 0.f;
  if (row < EF) {
    const float* wtr = Wt + row * HID;
    for (int i = 0; i < HID; ++i) s += wtr[i] * Wel[i * HID + j];
    Mt[(l * EF + row) * HID + pslot(j)] = s;
  } else {
    for (int i = 0; i < HID; ++i) s += bt[i] * Wel[i * HID + j];
    ct[l * HID + pslot(j)] = s;
  }
}

// x0 (fp32) -> bf16
__global__ __launch_bounds__(256) void k_cvtx(const float* __restrict__ x,
                                              unsigned short* __restrict__ xbf) {
  int id = blockIdx.x * 256 + threadIdx.x;  // one per 8 elements
  const int total = N_NODES * HID / 8;
  if (id >= total) return;
  const float4* p = (const float4*)(x + id * 8);
  float4 a = p[0], b = p[1];
  unsigned short o[8] = {f2bf(a.x), f2bf(a.y), f2bf(a.z), f2bf(a.w),
                         f2bf(b.x), f2bf(b.y), f2bf(b.z), f2bf(b.w)};
  *(uint4*)(xbf + id * 8) = *(uint4*)o;
}

// WT_bf[l][s][n][k] = bf16( W_s[l][k][n] ),  s=0 -> Wl, s=1 -> Wr
__global__ __launch_bounds__(256) void k_cvtw(const float* __restrict__ Wl,
                                              const float* __restrict__ Wr,
                                              unsigned short* __restrict__ WT) {
  int id = blockIdx.x * 256 + threadIdx.x;
  const int total = NLAYERS * 2 * HID * HID;
  if (id >= total) return;
  int k = id & (HID - 1);
  int n = (id >> 7) & (HID - 1);
  int s = (id >> 14) & 1;
  int l = id >> 15;
  const float* W = (s == 0 ? Wl : Wr) + (size_t)l * HID * HID;
  WT[id] = f2bf(W[k * HID + n]);
}

__global__ __launch_bounds__(256) void k_zero(int* __restrict__ counts, int* __restrict__ fill) {
  int id = blockIdx.x * 256 + threadIdx.x;
  if (id < N_NODES) { counts[id] = 0; fill[id] = 0; }
}

__global__ __launch_bounds__(256) void k_hist(const int* __restrict__ dst, int* __restrict__ counts) {
  int e = blockIdx.x * 256 + threadIdx.x;
  if (e < N_EDGES) atomicAdd(&counts[dst[e]], 1);
}

__global__ __launch_bounds__(256) void k_scan1(const int* __restrict__ counts,
                                               int* __restrict__ rowptr,
                                               int* __restrict__ bsum) {
  __shared__ int sc[256];
  int t = threadIdx.x;
  int i = blockIdx.x * 256 + t;
  int v = (i < N_NODES) ? counts[i] : 0;
  sc[t] = v;
  __syncthreads();
  for (int off = 1; off < 256; off <<= 1) {
    int u = 0;
    if (t >= off) u = sc[t - off];
    __syncthreads();
    sc[t] += u;
    __syncthreads();
  }
  if (i < N_NODES) rowptr[i] = sc[t] - v;  // block-local exclusive
  if (t == 255) bsum[blockIdx.x] = sc[255];
}

__global__ __launch_bounds__(256) void k_scan2(int* __restrict__ bsum) {
  __shared__ int sc[256];
  int t = threadIdx.x;
  int v = (t < SCAN_BLOCKS) ? bsum[t] : 0;
  sc[t] = v;
  __syncthreads();
  for (int off = 1; off < 256; off <<= 1) {
    int u = 0;
    if (t >= off) u = sc[t - off];
    __syncthreads();
    sc[t] += u;
    __syncthreads();
  }
  bsum[t] = sc[t] - v;  // exclusive block offsets
}

__global__ __launch_bounds__(256) void k_scan3(int* __restrict__ rowptr, const int* __restrict__ bsum) {
  int t = threadIdx.x;
  int i = blockIdx.x * 256 + t;
  if (i < N_NODES) rowptr[i] += bsum[blockIdx.x];
  if (i == 0) rowptr[N_NODES] = N_EDGES;
}

__global__ __launch_bounds__(256) void k_fill(const int* __restrict__ src,
                                              const int* __restrict__ dst,
                                              const int* __restrict__ rowptr,
                                              int* __restrict__ fill,
                                              int* __restrict__ ssrc,
                                              int* __restrict__ seid) {
  int e = blockIdx.x * 256 + threadIdx.x;
  if (e >= N_EDGES) return;
  int d = dst[e];
  int pos = atomicAdd(&fill[d], 1);
  int idx = rowptr[d] + pos;
  ssrc[idx] = src[e];
  seid[idx] = e;
}

// bf16 MFMA node GEMM: out_s = x @ W_s + b_s, channel-PAIRED layout.
// s=0 (xl): written as bf16 (gather table, halves gather traffic).
// s=1 (xr): written as fp32.
__global__ __launch_bounds__(256) void k_gemm_mfma(const unsigned short* __restrict__ xbf,
                                                   const unsigned short* __restrict__ WTl,  // layer base: [2][128][128]
                                                   const float* __restrict__ bl,
                                                   const float* __restrict__ br,
                                                   unsigned short* __restrict__ xlb,  // paired bf16
                                                   float* __restrict__ xr) {          // paired fp32
  __shared__ short As[64 * 136];
  __shared__ short Bs[128 * 136];
  int t = threadIdx.x;
  int s = blockIdx.y;
  int row0 = blockIdx.x * 64;

  // stage A: 64 rows x 128 bf16, 16B chunks
  const uint4* gx = (const uint4*)xbf;
#pragma unroll
  for (int p = 0; p < 4; ++p) {
    int c = t + p * 256;
    int row = c >> 4, col16 = c & 15;
    int grow = row0 + row;
    if (grow >= N_NODES) grow = N_NODES - 1;
    uint4 v = gx[grow * 16 + col16];
    *(uint4*)(&As[row * 136 + col16 * 8]) = v;
  }
  // stage B: 128 rows (n) x 128 bf16 of WT[s]
  const uint4* gw = (const uint4*)WTl;
#pragma unroll
  for (int p = 0; p < 8; ++p) {
    int c = t + p * 256;
    int row = c >> 4, col16 = c & 15;
    uint4 v = gw[s * 2048 + row * 16 + col16];
    *(uint4*)(&Bs[row * 136 + col16 * 8]) = v;
  }
  __syncthreads();

  int lane = t & 63, w = t >> 6;
  int quad = lane >> 4, lm = lane & 15;
  f32x4 acc[4][2];
#pragma unroll
  for (int mf = 0; mf < 4; ++mf)
#pragma unroll
    for (int nf = 0; nf < 2; ++nf) acc[mf][nf] = (f32x4)(0.f);

#pragma unroll
  for (int ks = 0; ks < 4; ++ks) {
    short8 af[4], bf[2];
#pragma unroll
    for (int mf = 0; mf < 4; ++mf)
      af[mf] = *(short8*)(&As[(mf * 16 + lm) * 136 + ks * 32 + quad * 8]);
#pragma unroll
    for (int nf = 0; nf < 2; ++nf)
      bf[nf] = *(short8*)(&Bs[(w * 32 + nf * 16 + lm) * 136 + ks * 32 + quad * 8]);
#pragma unroll
    for (int mf = 0; mf < 4; ++mf)
#pragma unroll
      for (int nf = 0; nf < 2; ++nf)
        acc[mf][nf] = __builtin_amdgcn_mfma_f32_16x16x32_bf16(af[mf], bf[nf], acc[mf][nf], 0, 0, 0);
  }

  const float* bias = (s == 0) ? bl : br;
#pragma unroll
  for (int nf = 0; nf < 2; ++nf) {
    int n = w * 32 + nf * 16 + lm;
    float bv = bias[n];
    int slot = pslot(n);
#pragma unroll
    for (int mf = 0; mf < 4; ++mf) {
#pragma unroll
      for (int r = 0; r < 4; ++r) {
        int grow = row0 + mf * 16 + quad * 4 + r;
        if (grow < N_NODES) {
          float val = acc[mf][nf][r] + bv;
          if (s == 0) xlb[(size_t)grow * HID + slot] = f2bf(val);
          else        xr [(size_t)grow * HID + slot] = val;
        }
      }
    }
  }
}

// ONE WAVE per destination node; lane l owns channels j0=(l>>3)*16+(l&7) and
// j0+8 (same head -> one 8-lane DPP reduce + one exp per edge). xl gathered
// as paired bf16 (one dword/lane); edge loop 2x unrolled for MLP.
__global__ __launch_bounds__(64) void k_fused(const float* __restrict__ xin,
                                              const unsigned int* __restrict__ xlb,  // paired bf16 (dword = 2 ch)
                                              const float* __restrict__ xr,          // paired fp32
                                              const float* __restrict__ eattr,
                                              const int* __restrict__ rowptr,
                                              const int* __restrict__ ssrc,
                                              const int* __restrict__ seid,
                                              const float* __restrict__ Mt,   // paired cols
                                              const float* __restrict__ ct,   // paired
                                              const float* __restrict__ att,
                                              const float* __restrict__ bias_o,
                                              const float* __restrict__ lng,
                                              const float* __restrict__ lnb,
                                              float* __restrict__ xout,
                                              unsigned short* __restrict__ xbf_out) {
  __shared__ float ea_s[CHUNK][EF];
  __shared__ int src_s[CHUNK];
  int n = blockIdx.x;
  int l = threadIdx.x;  // lane 0..63
  int j0 = (l >> 3) * 16 + (l & 7), j1 = j0 + 8;
  f32x2 mtp[EF];
#pragma unroll
  for (int k = 0; k < EF; ++k) mtp[k] = *(const f32x2*)(&Mt[k * HID + l * 2]);
  f32x2 base = *(const f32x2*)(&xr[(size_t)n * HID + l * 2]) +
               *(const f32x2*)(&ct[l * 2]);
  f32x2 attp = {att[j0], att[j1]};
  int beg = rowptr[n], end = rowptr[n + 1];
  f32x2 acc = {0.f, 0.f};
  float denom = 0.f;

  for (int c0 = beg; c0 < end; c0 += CHUNK) {
    int cnt = min(CHUNK, end - c0);
    __syncthreads();
    if (l < cnt) src_s[l] = ssrc[c0 + l];
    for (int q = l; q < cnt * 4; q += 64) {
      int i = q >> 2, part = q & 3;
      int e = seid[c0 + i];
      *(float4*)(&ea_s[i][part * 4]) = *(const float4*)(eattr + e * EF + part * 4);
    }
    __syncthreads();

    auto edge = [&](int i, unsigned int u) {
      f32x2 xls;
      xls.x = __uint_as_float(u << 16);
      xls.y = __uint_as_float(u & 0xFFFF0000u);
      f32x2 m = base + xls;
#pragma unroll
      for (int k = 0; k < EF; ++k) m += ea_s[i][k] * mtp[k];
      // leaky_relu(m, 0.2) = 0.6*m + 0.4*|m|
      f32x2 am = {__int_as_float(__float_as_int(m.x) & 0x7FFFFFFF),
                  __int_as_float(__float_as_int(m.y) & 0x7FFFFFFF)};
      m = 0.6f * m + 0.4f * am;
      f32x2 v2 = m * attp;
      float vs = dpp_hadd8(v2.x + v2.y);  // head logit (8 lanes share head)
      float p = __expf(vs);               // logits small: no max-subtract
      denom += p;
      acc += xls * p;
    };

    int i = 0;
    for (; i + 2 <= cnt; i += 2) {
      int s0 = src_s[i], s1 = src_s[i + 1];
      unsigned int u0 = xlb[(size_t)s0 * 64 + l];  // both issued before use
      unsigned int u1 = xlb[(size_t)s1 * 64 + l];
      edge(i, u0);
      edge(i + 1, u1);
    }
    if (i < cnt) {
      int s0 = src_s[i];
      edge(i, xlb[(size_t)s0 * 64 + l]);
    }
  }

  f32x2 outp;
  float inv = 1.f / (denom + 1e-16f);
  outp.x = acc.x * inv + bias_o[j0];
  outp.y = acc.y * inv + bias_o[j1];
  // LayerNorm over 128 channels: pair-sum then 64-lane butterfly (single wave)
  float s1 = outp.x + outp.y;
  float s2 = outp.x * outp.x + outp.y * outp.y;
#pragma unroll
  for (int mask = 1; mask <= 32; mask <<= 1) {
    s1 += __shfl_xor(s1, mask);
    s2 += __shfl_xor(s2, mask);
  }
  float mu = s1 * (1.f / 128.f);
  float var = s2 * (1.f / 128.f) - mu * mu;
  float rs = rsqrtf(var + 1e-5f);
  float y0 = lng[j0] * (outp.x - mu) * rs + lnb[j0];
  float y1 = lng[j1] * (outp.y - mu) * rs + lnb[j1];
  float r0 = fmaxf(y0, 0.f) + xin[(size_t)n * HID + j0];
  float r1 = fmaxf(y1, 0.f) + xin[(size_t)n * HID + j1];
  xout[(size_t)n * HID + j0] = r0;
  xout[(size_t)n * HID + j1] = r1;
  xbf_out[(size_t)n * HID + j0] = f2bf(r0);
  xbf_out[(size_t)n * HID + j1] = f2bf(r1);
}

extern "C" void kernel_launch(void* const* d_in, const int* in_sizes, int n_in,
                              void* d_out, int out_size, void* d_ws, size_t ws_size,
                              hipStream_t stream) {
  const float* x0    = (const float*)d_in[0];
  const int*   eidx  = (const int*)d_in[2];
  const float* eattr = (const float*)d_in[3];
  const float* Wt    = (const float*)d_in[4];
  const float* bt    = (const float*)d_in[5];
  const float* Wl    = (const float*)d_in[6];
  const float* bl    = (const float*)d_in[7];
  const float* Wr    = (const float*)d_in[8];
  const float* br    = (const float*)d_in[9];
  const float* We    = (const float*)d_in[10];
  const float* att   = (const float*)d_in[11];
  const float* bo    = (const float*)d_in[12];
  const float* lng   = (const float*)d_in[13];
  const float* lnb   = (const float*)d_in[14];
  float* out = (float*)d_out;
  const int* src = eidx;
  const int* dst = eidx + N_EDGES;

  char* ws = (char*)d_ws;
  size_t off = 0;
  auto alloc = [&](size_t bytes) {
    char* p = ws + off;
    off += (bytes + 255) & ~(size_t)255;
    return p;
  };
  float* Mt   = (float*)alloc((size_t)NLAYERS * EF * HID * 4);
  float* ct   = (float*)alloc((size_t)NLAYERS * HID * 4);
  int* counts = (int*)alloc((size_t)N_NODES * 4);
  int* rowptr = (int*)alloc((size_t)(N_NODES + 1) * 4);
  int* bsum   = (int*)alloc(256 * 4);
  int* fill   = (int*)alloc((size_t)N_NODES * 4);
  int* ssrc   = (int*)alloc((size_t)N_EDGES * 4);
  int* seid   = (int*)alloc((size_t)N_EDGES * 4);
  unsigned short* xlb = (unsigned short*)alloc((size_t)N_NODES * HID * 2);
  float* xr   = (float*)alloc((size_t)N_NODES * HID * 4);
  float* xbuf = (float*)alloc((size_t)N_NODES * HID * 4);
  unsigned short* xbf = (unsigned short*)alloc((size_t)N_NODES * HID * 2);
  unsigned short* WTb = (unsigned short*)alloc((size_t)NLAYERS * 2 * HID * HID * 2);

  hipLaunchKernelGGL(k_prep, dim3(26), dim3(256), 0, stream, Wt, bt, We, Mt, ct);
  hipLaunchKernelGGL(k_cvtx, dim3((N_NODES * HID / 8 + 255) / 256), dim3(256), 0, stream, x0, xbf);
  hipLaunchKernelGGL(k_cvtw, dim3((NLAYERS * 2 * HID * HID + 255) / 256), dim3(256), 0, stream, Wl, Wr, WTb);
  hipLaunchKernelGGL(k_zero, dim3(SCAN_BLOCKS), dim3(256), 0, stream, counts, fill);
  hipLaunchKernelGGL(k_hist, dim3((N_EDGES + 255) / 256), dim3(256), 0, stream, dst, counts);
  hipLaunchKernelGGL(k_scan1, dim3(SCAN_BLOCKS), dim3(256), 0, stream, counts, rowptr, bsum);
  hipLaunchKernelGGL(k_scan2, dim3(1), dim3(256), 0, stream, bsum);
  hipLaunchKernelGGL(k_scan3, dim3(SCAN_BLOCKS), dim3(256), 0, stream, rowptr, bsum);
  hipLaunchKernelGGL(k_fill, dim3((N_EDGES + 255) / 256), dim3(256), 0, stream,
                     src, dst, rowptr, fill, ssrc, seid);

  for (int l = 0; l < NLAYERS; ++l) {
    const float* xin = (l == 0) ? x0 : (const float*)xbuf;
    float* xout = (l == NLAYERS - 1) ? out : xbuf;
    hipLaunchKernelGGL(k_gemm_mfma, dim3((N_NODES + 63) / 64, 2), dim3(256), 0, stream,
                       xbf, WTb + (size_t)l * 2 * HID * HID, bl + l * HID, br + l * HID, xlb, xr);
    hipLaunchKernelGGL(k_fused, dim3(N_NODES), dim3(64), 0, stream,
                       xin, (const unsigned int*)xlb, xr, eattr, rowptr, ssrc, seid,
                       Mt + (size_t)l * EF * HID, ct + l * HID, att + l * HID,
                       bo + l * HID, lng + l * HID, lnb + l * HID, xout, xbf);
  }
}